// Round 7
// baseline (1551.244 us; speedup 1.0000x reference)
//
#include <hip/hip_runtime.h>

#define T_STEPS 1000
#define IN 13
#define HID 32
#define NGRP 250            // 4-step x groups
// per-elem LDS float offsets
#define XOFF  0             // x slots: [8][16] (two 4-step halves)
#define H0OFF 128           // h0: [2][32]
#define H1OFF 192           // h1: [2][32]
#define EFLOATS 256         // 1 KiB per element

typedef float v2f __attribute__((ext_vector_type(2)));

// ---- packed f32 FMA, z-scalar broadcast variants ----
// acc.lo += z_sel * w.lo ; acc.hi += z_sel * w.hi   (w = row pair, z = shared operand)
__device__ __forceinline__ void pk_fma_zlo(v2f& acc, v2f z, v2f w) {
    asm("v_pk_fma_f32 %0, %1, %2, %0 op_sel:[0,0,0] op_sel_hi:[0,1,1]"
        : "+v"(acc) : "v"(z), "v"(w));
}
__device__ __forceinline__ void pk_fma_zhi(v2f& acc, v2f z, v2f w) {
    asm("v_pk_fma_f32 %0, %1, %2, %0 op_sel:[1,0,0] op_sel_hi:[1,1,1]"
        : "+v"(acc) : "v"(z), "v"(w));
}

#define DPP_XOR1 0xB1       // quad perm [1,0,3,2]: exchange lane pairs
template<int CTRL>
__device__ __forceinline__ float dpp_qp(float x) {
    return __int_as_float(__builtin_amdgcn_update_dpp(
        0, __float_as_int(x), CTRL, 0xF, 0xF, true));
}

// ONE WAVE = ONE BATCH ELEMENT, BOTH LAYERS. Block = 256 thr = 4 independent waves
// (4 elems), grid 512 -> 2 blocks/CU, 2 waves/SIMD, 256-VGPR budget.
//
// Lane pair (2u, 2u+1) owns unit u of BOTH layers: even lane rows (i,f), odd (g,o).
// Weights: per lane 109 v2f row-pairs (L0: 13 x + 32 h; L1: 32 ih + 32 hh), preshifted
// to exp2 domain (sigmoid rows * -log2e, tanh rows * -2log2e).
// Iteration k: L0 step k (h0[k-1], x[k]) + L1 step k-1 (h0[k-1], h1[k-2]) -- the two
// dots share the h0 reads and are mutually independent -> deep ILP, and ALL state is
// wave-private LDS: NO __syncthreads anywhere in the time loop.
// Epilogue per layer: 2 exp2 chains, 1 DPP pair-exchange (partner's tanh-g / sig-o),
// cell update valid on even lanes, h write by even lanes (32 consecutive -> no bank
// conflicts). Reads are wave-uniform broadcasts (conflict-free).
__global__ __launch_bounds__(256, 2)
void lstm_fused(const float* __restrict__ X,
                const float* __restrict__ Wih0, const float* __restrict__ Whh0,
                const float* __restrict__ bih0, const float* __restrict__ bhh0,
                const float* __restrict__ Wih1, const float* __restrict__ Whh1,
                const float* __restrict__ bih1, const float* __restrict__ bhh1,
                const float* __restrict__ Wc1,  const float* __restrict__ bc1,
                const float* __restrict__ Wc2,  const float* __restrict__ bc2,
                float* __restrict__ out)
{
    const int tid = threadIdx.x;
    const int wv  = tid >> 6;               // wave in block = elem slot
    const int l   = tid & 63;
    const int u   = l >> 1;                 // unit 0..31
    const int odd = l & 1;                  // 0: rows (i,f); 1: rows (g,o)
    const int e   = blockIdx.x * 4 + wv;    // global batch element

    __shared__ __align__(16) float smem_all[4 * EFLOATS];
    float* sm = smem_all + wv * EFLOATS;

    const float SCL = -1.44269504088896340736f;   // -log2(e)
    const float C2  = 2.f * SCL;
    // row0 = gate i (even) / g (odd); row1 = gate f (even) / o (odd)
    const int   r0 = (odd ? 2 : 0) * HID + u;
    const int   r1 = (odd ? 3 : 1) * HID + u;
    const float s0 = odd ? 2.f * SCL : SCL;       // g-gate gets tanh scaling
    const float s1 = SCL;
    const float actA0 = odd ? 2.f : 1.f;          // row0 act: tanh (odd) / sigmoid
    const float actB0 = odd ? -1.f : 0.f;

    // ---- per-lane weights: row-pair packed, pre-scaled ----
    v2f wx[IN], wh0[HID], w1a[HID], w1h[HID], b0, b1;
    #pragma unroll
    for (int i = 0; i < IN; ++i)
        wx[i] = (v2f){Wih0[r0*IN + i] * s0, Wih0[r1*IN + i] * s1};
    #pragma unroll
    for (int j = 0; j < HID; ++j) {
        wh0[j] = (v2f){Whh0[r0*HID + j] * s0, Whh0[r1*HID + j] * s1};
        w1a[j] = (v2f){Wih1[r0*HID + j] * s0, Wih1[r1*HID + j] * s1};
        w1h[j] = (v2f){Whh1[r0*HID + j] * s0, Whh1[r1*HID + j] * s1};
    }
    b0 = (v2f){(bih0[r0] + bhh0[r0]) * s0, (bih0[r1] + bhh0[r1]) * s1};
    b1 = (v2f){(bih1[r0] + bhh1[r0]) * s0, (bih1[r1] + bhh1[r1]) * s1};

    // ---- init: zero h1[-1] (parity 0); stage x group 0, prefetch group 1 ----
    if (l < HID) sm[H1OFF + l] = 0.f;

    const bool stg = (l < IN);              // 13 stager lanes
    const float* xg = X + (size_t)e * (T_STEPS * IN) + l * 4;
    int xo0 = 0, xo1 = 0, xo2 = 0, xo3 = 0;
    float4 xr = make_float4(0.f, 0.f, 0.f, 0.f);
    if (stg) {
        const int f0 = l * 4;
        xo0 = ((f0    ) / IN) * 16 + (f0    ) % IN;
        xo1 = ((f0 + 1) / IN) * 16 + (f0 + 1) % IN;
        xo2 = ((f0 + 2) / IN) * 16 + (f0 + 2) % IN;
        xo3 = ((f0 + 3) / IN) * 16 + (f0 + 3) % IN;
        float4 x0 = *(const float4*)xg;                 // group 0 -> half 0
        sm[XOFF + xo0] = x0.x; sm[XOFF + xo1] = x0.y;
        sm[XOFF + xo2] = x0.z; sm[XOFF + xo3] = x0.w;
        xr = *(const float4*)(xg + 52);                 // prefetch group 1
    }

    float cd0 = 0.f, cd1 = 0.f;   // cell states; VALID ON EVEN LANES ONLY

    // ================= k = 0 (peeled): L0 only, h0[-1]=0 -> x-part + bias =========
    {
        v2f a00 = b0, a01 = {0.f,0.f}, a02 = {0.f,0.f}, a03 = {0.f,0.f};
        const float* xp = sm + XOFF;                    // slot 0
        float4 z0 = *(const float4*)(xp);
        float4 z1 = *(const float4*)(xp + 4);
        float4 z2 = *(const float4*)(xp + 8);
        float  xc = xp[12];
        v2f za = {z0.x, z0.y}, zb = {z0.z, z0.w};
        pk_fma_zlo(a00, za, wx[0]);  pk_fma_zhi(a01, za, wx[1]);
        pk_fma_zlo(a02, zb, wx[2]);  pk_fma_zhi(a03, zb, wx[3]);
        za = (v2f){z1.x, z1.y}; zb = (v2f){z1.z, z1.w};
        pk_fma_zlo(a00, za, wx[4]);  pk_fma_zhi(a01, za, wx[5]);
        pk_fma_zlo(a02, zb, wx[6]);  pk_fma_zhi(a03, zb, wx[7]);
        za = (v2f){z2.x, z2.y}; zb = (v2f){z2.z, z2.w};
        pk_fma_zlo(a00, za, wx[8]);  pk_fma_zhi(a01, za, wx[9]);
        pk_fma_zlo(a02, zb, wx[10]); pk_fma_zhi(a03, zb, wx[11]);
        v2f zc = {xc, xc};
        pk_fma_zlo(a00, zc, wx[12]);
        v2f S = (a00 + a01) + (a02 + a03);
        float v00 = fmaf(actA0, __builtin_amdgcn_rcpf(1.f + exp2f(S.x)), actB0);
        float v01 = __builtin_amdgcn_rcpf(1.f + exp2f(S.y));
        float t00 = dpp_qp<DPP_XOR1>(v00);
        float t01 = dpp_qp<DPP_XOR1>(v01);
        cd0 = fmaf(v01, cd0, v00 * t00);                // f*c + i*g (even lanes)
        float th = fmaf(2.f, __builtin_amdgcn_rcpf(1.f + exp2f(cd0 * C2)), -1.f);
        float hv = t01 * th;
        if (!odd) sm[H0OFF + 0 * HID + u] = hv;         // h0_0 -> parity 0
        // stage: group 1 -> half 1, prefetch group 2
        if (stg) {
            sm[XOFF + 64 + xo0] = xr.x; sm[XOFF + 64 + xo1] = xr.y;
            sm[XOFF + 64 + xo2] = xr.z; sm[XOFF + 64 + xo3] = xr.w;
            xr = *(const float4*)(xg + 2 * 52);
        }
    }

    // ================= main loop k = 1..999: L0 step k + L1 step k-1, no barriers ==
    #pragma unroll 1
    for (int k = 1; k < T_STEPS; ++k) {
        const int grp = k >> 2;
        if ((k & 3) == 0 && stg) {
            if (grp + 1 < NGRP) {
                const int hb = ((grp + 1) & 1) << 6;
                sm[XOFF + hb + xo0] = xr.x; sm[XOFF + hb + xo1] = xr.y;
                sm[XOFF + hb + xo2] = xr.z; sm[XOFF + hb + xo3] = xr.w;
            }
            if (grp + 2 < NGRP) xr = *(const float4*)(xg + (size_t)(grp + 2) * 52);
        }
        const int rp  = (k + 1) & 1;                    // read parity (state k-1/k-2)
        const int wpp = k & 1;                          // write parity
        const float* h0p = sm + H0OFF + rp * HID;
        const float* h1p = sm + H1OFF + rp * HID;
        const float* xp  = sm + XOFF + ((k & 7) << 4);

        v2f a00 = b0, a01 = {0.f,0.f}, a02 = {0.f,0.f}, a03 = {0.f,0.f};
        v2f a10 = b1, a11 = {0.f,0.f}, a12 = {0.f,0.f}, a13 = {0.f,0.f};

        // shared h0_{k-1} reads feed BOTH the L0 h-part and the L1 ih-part
        #pragma unroll
        for (int jj = 0; jj < 8; ++jj) {
            float4 z = *(const float4*)(h0p + jj * 4);
            v2f za = {z.x, z.y}, zb = {z.z, z.w};
            pk_fma_zlo(a00, za, wh0[4*jj+0]); pk_fma_zhi(a01, za, wh0[4*jj+1]);
            pk_fma_zlo(a02, zb, wh0[4*jj+2]); pk_fma_zhi(a03, zb, wh0[4*jj+3]);
            pk_fma_zlo(a10, za, w1a[4*jj+0]); pk_fma_zhi(a11, za, w1a[4*jj+1]);
            pk_fma_zlo(a12, zb, w1a[4*jj+2]); pk_fma_zhi(a13, zb, w1a[4*jj+3]);
        }
        // L1 hh-part: h1_{k-2}
        #pragma unroll
        for (int jj = 0; jj < 8; ++jj) {
            float4 z = *(const float4*)(h1p + jj * 4);
            v2f za = {z.x, z.y}, zb = {z.z, z.w};
            pk_fma_zlo(a10, za, w1h[4*jj+0]); pk_fma_zhi(a11, za, w1h[4*jj+1]);
            pk_fma_zlo(a12, zb, w1h[4*jj+2]); pk_fma_zhi(a13, zb, w1h[4*jj+3]);
        }
        // L0 x-part: x_k
        {
            float4 z0 = *(const float4*)(xp);
            float4 z1 = *(const float4*)(xp + 4);
            float4 z2 = *(const float4*)(xp + 8);
            float  xc = xp[12];
            v2f za = {z0.x, z0.y}, zb = {z0.z, z0.w};
            pk_fma_zlo(a00, za, wx[0]);  pk_fma_zhi(a01, za, wx[1]);
            pk_fma_zlo(a02, zb, wx[2]);  pk_fma_zhi(a03, zb, wx[3]);
            za = (v2f){z1.x, z1.y}; zb = (v2f){z1.z, z1.w};
            pk_fma_zlo(a00, za, wx[4]);  pk_fma_zhi(a01, za, wx[5]);
            pk_fma_zlo(a02, zb, wx[6]);  pk_fma_zhi(a03, zb, wx[7]);
            za = (v2f){z2.x, z2.y}; zb = (v2f){z2.z, z2.w};
            pk_fma_zlo(a00, za, wx[8]);  pk_fma_zhi(a01, za, wx[9]);
            pk_fma_zlo(a02, zb, wx[10]); pk_fma_zhi(a03, zb, wx[11]);
            v2f zc = {xc, xc};
            pk_fma_zlo(a00, zc, wx[12]);
        }

        // ---- L0 epilogue ----
        {
            v2f S = (a00 + a01) + (a02 + a03);
            float v00 = fmaf(actA0, __builtin_amdgcn_rcpf(1.f + exp2f(S.x)), actB0);
            float v01 = __builtin_amdgcn_rcpf(1.f + exp2f(S.y));
            float t00 = dpp_qp<DPP_XOR1>(v00);
            float t01 = dpp_qp<DPP_XOR1>(v01);
            cd0 = fmaf(v01, cd0, v00 * t00);
            float th = fmaf(2.f, __builtin_amdgcn_rcpf(1.f + exp2f(cd0 * C2)), -1.f);
            float hv = t01 * th;
            if (!odd) sm[H0OFF + wpp * HID + u] = hv;   // h0_k
        }
        // ---- L1 epilogue ----
        {
            v2f S = (a10 + a11) + (a12 + a13);
            float v00 = fmaf(actA0, __builtin_amdgcn_rcpf(1.f + exp2f(S.x)), actB0);
            float v01 = __builtin_amdgcn_rcpf(1.f + exp2f(S.y));
            float t00 = dpp_qp<DPP_XOR1>(v00);
            float t01 = dpp_qp<DPP_XOR1>(v01);
            cd1 = fmaf(v01, cd1, v00 * t00);
            float th = fmaf(2.f, __builtin_amdgcn_rcpf(1.f + exp2f(cd1 * C2)), -1.f);
            float hv = t01 * th;
            if (!odd) sm[H1OFF + wpp * HID + u] = hv;   // h1_{k-1}
        }
    }

    // ================= k = 1000 (peeled): L1 step 999 only =======================
    {
        const float* h0p = sm + H0OFF + 1 * HID;        // h0_999 (parity 1)
        const float* h1p = sm + H1OFF + 1 * HID;        // h1_998 (parity 1)
        v2f a10 = b1, a11 = {0.f,0.f}, a12 = {0.f,0.f}, a13 = {0.f,0.f};
        #pragma unroll
        for (int jj = 0; jj < 8; ++jj) {
            float4 z = *(const float4*)(h0p + jj * 4);
            v2f za = {z.x, z.y}, zb = {z.z, z.w};
            pk_fma_zlo(a10, za, w1a[4*jj+0]); pk_fma_zhi(a11, za, w1a[4*jj+1]);
            pk_fma_zlo(a12, zb, w1a[4*jj+2]); pk_fma_zhi(a13, zb, w1a[4*jj+3]);
        }
        #pragma unroll
        for (int jj = 0; jj < 8; ++jj) {
            float4 z = *(const float4*)(h1p + jj * 4);
            v2f za = {z.x, z.y}, zb = {z.z, z.w};
            pk_fma_zlo(a10, za, w1h[4*jj+0]); pk_fma_zhi(a11, za, w1h[4*jj+1]);
            pk_fma_zlo(a12, zb, w1h[4*jj+2]); pk_fma_zhi(a13, zb, w1h[4*jj+3]);
        }
        v2f S = (a10 + a11) + (a12 + a13);
        float v00 = fmaf(actA0, __builtin_amdgcn_rcpf(1.f + exp2f(S.x)), actB0);
        float v01 = __builtin_amdgcn_rcpf(1.f + exp2f(S.y));
        float t00 = dpp_qp<DPP_XOR1>(v00);
        float t01 = dpp_qp<DPP_XOR1>(v01);
        cd1 = fmaf(v01, cd1, v00 * t00);
        float th = fmaf(2.f, __builtin_amdgcn_rcpf(1.f + exp2f(cd1 * C2)), -1.f);
        float hv = t01 * th;
        if (!odd) sm[H1OFF + 0 * HID + u] = hv;         // h1_999 -> parity 0
    }

    // ================= classifier head, fully wave-local ==========================
    // hidden = relu(Wc1 @ h1 + bc1) -> reuse x area as hidbuf; out = Wc2 @ hidden + bc2
    if (l < HID) {
        float acc = bc1[l];
        #pragma unroll
        for (int j = 0; j < HID; ++j)
            acc = fmaf(Wc1[l*HID + j], sm[H1OFF + j], acc);
        sm[XOFF + l] = fmaxf(acc, 0.f);
    }
    if (l < 3) {
        float vv = bc2[l];
        #pragma unroll
        for (int j = 0; j < HID; ++j)
            vv = fmaf(Wc2[l*HID + j], sm[XOFF + j], vv);
        out[e * 3 + l] = vv;
    }
}

extern "C" void kernel_launch(void* const* d_in, const int* in_sizes, int n_in,
                              void* d_out, int out_size, void* d_ws, size_t ws_size,
                              hipStream_t stream) {
    const float* X    = (const float*)d_in[0];
    const float* Wih0 = (const float*)d_in[1];
    const float* Whh0 = (const float*)d_in[2];
    const float* bih0 = (const float*)d_in[3];
    const float* bhh0 = (const float*)d_in[4];
    const float* Wih1 = (const float*)d_in[5];
    const float* Whh1 = (const float*)d_in[6];
    const float* bih1 = (const float*)d_in[7];
    const float* bhh1 = (const float*)d_in[8];
    const float* Wc1  = (const float*)d_in[9];
    const float* bc1  = (const float*)d_in[10];
    const float* Wc2  = (const float*)d_in[11];
    const float* bc2  = (const float*)d_in[12];

    lstm_fused<<<512, 256, 0, stream>>>(X, Wih0, Whh0, bih0, bhh0,
                                        Wih1, Whh1, bih1, bhh1,
                                        Wc1, bc1, Wc2, bc2, (float*)d_out);
}